// Round 2
// baseline (857.201 us; speedup 1.0000x reference)
//
#include <hip/hip_runtime.h>

#define B_ 4
#define S_ 2048
#define H_ 2048
#define NH_ 8
#define NKV_ 4
#define HD_ 256
#define WINDOW_ 1024
#define SCALE_ 0.0625f

typedef __bf16 bf16x8 __attribute__((ext_vector_type(8)));
typedef float f32x4 __attribute__((ext_vector_type(4)));

__device__ __forceinline__ unsigned short f2bf(float f) {
  union { float f; unsigned u; } v; v.f = f;
  unsigned r = v.u + 0x7fffu + ((v.u >> 16) & 1u);
  return (unsigned short)(r >> 16);
}
__device__ __forceinline__ float bf2f(unsigned short h) {
  union { unsigned u; float f; } v; v.u = ((unsigned)h) << 16;
  return v.f;
}

__device__ __forceinline__ f32x4 mfma16(bf16x8 a, bf16x8 b, f32x4 c) {
  return __builtin_amdgcn_mfma_f32_16x16x32_bf16(a, b, c, 0, 0, 0);
}

#define GLOAD16(gsrc, ldst)                                                     \
  __builtin_amdgcn_global_load_lds(                                             \
      (const __attribute__((address_space(1))) void*)(gsrc),                    \
      (__attribute__((address_space(3))) void*)(ldst), 16, 0, 0)

// ---------------------------------------------------------------- convert ----
__global__ void f32_to_bf16(const float* __restrict__ in,
                            unsigned short* __restrict__ out, int n4) {
  int idx = blockIdx.x * blockDim.x + threadIdx.x;
  int stride = gridDim.x * blockDim.x;
  for (; idx < n4; idx += stride) {
    float4 v = reinterpret_cast<const float4*>(in)[idx];
    ushort4 o;
    o.x = f2bf(v.x); o.y = f2bf(v.y); o.z = f2bf(v.z); o.w = f2bf(v.w);
    reinterpret_cast<ushort4*>(out)[idx] = o;
  }
}

// in[R][C] fp32  ->  out[C][R] bf16
__global__ void transpose_w(const float* __restrict__ in,
                            unsigned short* __restrict__ out, int R, int C) {
  __shared__ unsigned short t[32][33];
  int r0 = blockIdx.x * 32, c0 = blockIdx.y * 32;
  int tx = threadIdx.x & 31, ty = threadIdx.x >> 5;  // ty 0..7
#pragma unroll
  for (int i = 0; i < 4; ++i)
    t[ty * 4 + i][tx] = f2bf(in[(size_t)(r0 + ty * 4 + i) * C + c0 + tx]);
  __syncthreads();
#pragma unroll
  for (int i = 0; i < 4; ++i)
    out[(size_t)(c0 + ty * 4 + i) * R + r0 + tx] = t[tx][ty * 4 + i];
}

// ------------------------------------------------------------------- GEMM ----
// C[M][N] = A[M][Kd] * Bt[N][Kd]^T + bias   (m97 structure, 128x128 tile,
// T1 XCD-aware bijective block swizzle — nwg must be a multiple of 8)
template <int OUT_F32>
__global__ __launch_bounds__(256) void gemm_kernel(
    const unsigned short* __restrict__ A, const unsigned short* __restrict__ Bt,
    const float* __restrict__ bias, void* __restrict__ Cout, int M, int N,
    int Kd) {
  __shared__ __align__(16) unsigned short As[128 * 32];
  __shared__ __align__(16) unsigned short Bs[128 * 32];
  const int tid = threadIdx.x, lane = tid & 63, wid = tid >> 6;
  const int lc = lane & 15, lg = lane >> 4;
  const int wm = wid >> 1, wn = wid & 1;
  // XCD swizzle: contiguous chunk of tiles per XCD (gridDim.x % 8 == 0)
  const int nwg = gridDim.x;
  const int cpx = nwg >> 3;
  const int wg = (blockIdx.x & 7) * cpx + (blockIdx.x >> 3);
  const int mtiles = M >> 7;
  const int m0 = (wg % mtiles) * 128, n0 = (wg / mtiles) * 128;
  f32x4 acc[4][4];
#pragma unroll
  for (int m = 0; m < 4; ++m)
#pragma unroll
    for (int n = 0; n < 4; ++n) acc[m][n] = f32x4{0.f, 0.f, 0.f, 0.f};

  const int nkt = Kd >> 5;
  for (int kt = 0; kt < nkt; ++kt) {
#pragma unroll
    for (int i = 0; i < 2; ++i) {
      int chunk = i * 256 + tid;
      int row = chunk >> 2, off = chunk & 3;
      const unsigned short* src = A + (size_t)(m0 + row) * Kd + kt * 32 + off * 8;
      unsigned ldsoff = (unsigned)(i * 256 + wid * 64) * 16;
      GLOAD16(src, (char*)As + ldsoff);
    }
#pragma unroll
    for (int i = 0; i < 2; ++i) {
      int chunk = i * 256 + tid;
      int row = chunk >> 2, off = chunk & 3;
      const unsigned short* src = Bt + (size_t)(n0 + row) * Kd + kt * 32 + off * 8;
      unsigned ldsoff = (unsigned)(i * 256 + wid * 64) * 16;
      GLOAD16(src, (char*)Bs + ldsoff);
    }
    asm volatile("s_waitcnt vmcnt(0)" ::: "memory");
    __syncthreads();
    bf16x8 af[4], bfr[4];
#pragma unroll
    for (int x = 0; x < 4; ++x) {
      af[x] = *reinterpret_cast<const bf16x8*>(As + ((wm * 64 + x * 16 + lc) * 32 + lg * 8));
      bfr[x] = *reinterpret_cast<const bf16x8*>(Bs + ((wn * 64 + x * 16 + lc) * 32 + lg * 8));
    }
#pragma unroll
    for (int m = 0; m < 4; ++m)
#pragma unroll
      for (int n = 0; n < 4; ++n) acc[m][n] = mfma16(af[m], bfr[n], acc[m][n]);
    __syncthreads();
  }
  // epilogue: C row = lg*4+r, col = lc (verified C/D layout)
#pragma unroll
  for (int m = 0; m < 4; ++m) {
#pragma unroll
    for (int n = 0; n < 4; ++n) {
      const int gcol = n0 + wn * 64 + n * 16 + lc;
      const float bv = bias ? bias[gcol] : 0.f;
      const int grow = m0 + wm * 64 + m * 16 + lg * 4;
#pragma unroll
      for (int r = 0; r < 4; ++r) {
        float v = acc[m][n][r] + bv;
        if (OUT_F32)
          reinterpret_cast<float*>(Cout)[(size_t)(grow + r) * N + gcol] = v;
        else
          reinterpret_cast<unsigned short*>(Cout)[(size_t)(grow + r) * N + gcol] = f2bf(v);
      }
    }
  }
}

// ------------------------------------------------------------------- RoPE ----
// in [B*S][nh*HD] bf16 -> out [B][nh][S][HD] bf16 with neox rope.
// One thread per (bs, d-pair); trig computed ONCE and reused across all heads.
__global__ void rope_kernel(const unsigned short* __restrict__ in,
                            const int* __restrict__ pos,
                            unsigned short* __restrict__ out, int nh) {
  int idx = blockIdx.x * 256 + threadIdx.x;  // B*S*128 threads
  int d = idx & 127;
  int bs = idx >> 7;
  int b = bs >> 11, s = bs & 2047;
  float p = (float)pos[bs];
  float inv = __expf(-(float)d * (9.210340371976184f / 128.f));
  float fr = p * inv;
  float cs, sn;
  sincosf(fr, &sn, &cs);
  const unsigned short* ib = in + (size_t)bs * (nh * HD_) + d;
  unsigned short* ob = out + ((size_t)b * nh * S_ + s) * HD_ + d;
  for (int hh = 0; hh < nh; ++hh) {
    float x1 = bf2f(ib[hh * HD_]);
    float x2 = bf2f(ib[hh * HD_ + 128]);
    ob[(size_t)hh * S_ * HD_] = f2bf(x1 * cs - x2 * sn);
    ob[(size_t)hh * S_ * HD_ + 128] = f2bf(x2 * cs + x1 * sn);
  }
}

// in [B*S][NKV*HD] bf16 -> out [B][NKV][HD][S] bf16
__global__ void transpose_v(const unsigned short* __restrict__ in,
                            unsigned short* __restrict__ out) {
  __shared__ unsigned short t[32][33];
  int s0 = blockIdx.x * 32, d0 = blockIdx.y * 32;
  int bh = blockIdx.z;
  int b = bh >> 2, hh = bh & 3;
  int tx = threadIdx.x & 31, ty = threadIdx.x >> 5;
#pragma unroll
  for (int i = 0; i < 4; ++i)
    t[ty * 4 + i][tx] =
        in[(size_t)(b * S_ + s0 + ty * 4 + i) * (NKV_ * HD_) + hh * HD_ + d0 + tx];
  __syncthreads();
#pragma unroll
  for (int i = 0; i < 4; ++i)
    out[((size_t)(b * NKV_ + hh) * HD_ + d0 + ty * 4 + i) * S_ + s0 + tx] =
        t[tx][ty * 4 + i];
}

// -------------------------------------------------------------- attention ----
// Q [B][NH][S][HD], K [B][NKV][S][HD], VT [B][NKV][HD][S] -> O [B*S][NH*HD]
// 4 waves x 16 q-rows, KVBLK=32, online softmax, sliding-window + causal mask.
__global__ __launch_bounds__(256) void attn_kernel(
    const unsigned short* __restrict__ Q, const unsigned short* __restrict__ K,
    const unsigned short* __restrict__ VT, unsigned short* __restrict__ O) {
  __shared__ __align__(16) unsigned short Kl[32 * 256];  // 16KB, swizzled
  __shared__ __align__(16) unsigned short Vl[256 * 32];  // 16KB, swizzled
  __shared__ __align__(16) unsigned short Pl[4][16 * 40]; // per-wave, +8 pad

  const int tid = threadIdx.x;
  const int lane = tid & 63, wid = tid >> 6;
  const int lc = lane & 15, lg = lane >> 4;
  const int qt = blockIdx.x, h = blockIdx.y, b = blockIdx.z;
  const int kvh = h >> 1;  // GQA: rep=2
  const int q0 = qt * 64;

  // Q fragments: A[row=lc][k = ds*32 + lg*8 + j]
  bf16x8 qf[8];
  const unsigned short* Qbase =
      Q + (((size_t)(b * NH_ + h)) * S_ + (q0 + wid * 16 + lc)) * HD_;
#pragma unroll
  for (int ds = 0; ds < 8; ++ds)
    qf[ds] = *reinterpret_cast<const bf16x8*>(Qbase + ds * 32 + lg * 8);

  f32x4 acc[16];
#pragma unroll
  for (int i = 0; i < 16; ++i) acc[i] = f32x4{0.f, 0.f, 0.f, 0.f};
  float m_r[4], l_r[4];
#pragma unroll
  for (int r = 0; r < 4; ++r) { m_r[r] = -1e30f; l_r[r] = 0.f; }

  const unsigned short* Kg0 = K + ((size_t)(b * NKV_ + kvh)) * S_ * HD_;
  const unsigned short* Vg0 = VT + ((size_t)(b * NKV_ + kvh)) * HD_ * S_;

  int jlo = q0 - (WINDOW_ - 1);
  if (jlo < 0) jlo = 0;
  const int jt_lo = jlo >> 5;
  const int jt_hi = (q0 + 63) >> 5;

  for (int jt = jt_lo; jt <= jt_hi; ++jt) {
    const int kv0 = jt * 32;
    // stage K tile [32 kv][256 d]: src pre-swizzled (involution with read)
#pragma unroll
    for (int i = 0; i < 4; ++i) {
      int chunk = i * 256 + tid;
      int row = chunk >> 5, o = chunk & 31;
      const unsigned short* src =
          Kg0 + (size_t)(kv0 + row) * HD_ + (o ^ (row & 7)) * 8;
      unsigned ldsoff = (unsigned)(i * 256 + wid * 64) * 16;
      GLOAD16(src, (char*)Kl + ldsoff);
    }
    // stage V^T tile [256 d][32 kv]
#pragma unroll
    for (int i = 0; i < 4; ++i) {
      int chunk = i * 256 + tid;
      int row = chunk >> 2, o = chunk & 3;
      const unsigned short* src =
          Vg0 + (size_t)row * S_ + kv0 + (o ^ ((row >> 1) & 3)) * 8;
      unsigned ldsoff = (unsigned)(i * 256 + wid * 64) * 16;
      GLOAD16(src, (char*)Vl + ldsoff);
    }
    asm volatile("s_waitcnt vmcnt(0)" ::: "memory");
    __syncthreads();

    // S = Q K^T : B operand = K rows (swizzled read)
    f32x4 sf[2];
    __builtin_amdgcn_s_setprio(1);
#pragma unroll
    for (int ct = 0; ct < 2; ++ct) {
      f32x4 s{0.f, 0.f, 0.f, 0.f};
      int j = ct * 16 + lc;
#pragma unroll
      for (int ds = 0; ds < 8; ++ds) {
        int g = ds * 4 + lg;
        const bf16x8 kf = *reinterpret_cast<const bf16x8*>(
            (const char*)Kl + (j * 512 + ((g ^ (j & 7)) * 16)));
        s = mfma16(qf[ds], kf, s);
      }
      sf[ct] = s;
    }
    __builtin_amdgcn_s_setprio(0);

    // mask + scale, row-max
    float sval[2][4];
    float pmax[4];
#pragma unroll
    for (int r = 0; r < 4; ++r) pmax[r] = -1e30f;
    const int ibase = q0 + wid * 16 + lg * 4;
#pragma unroll
    for (int ct = 0; ct < 2; ++ct) {
      int j = kv0 + ct * 16 + lc;
#pragma unroll
      for (int r = 0; r < 4; ++r) {
        int irow = ibase + r;
        bool ok = (j <= irow) && (j > irow - WINDOW_);
        float v = ok ? sf[ct][r] * SCALE_ : -1e30f;
        sval[ct][r] = v;
        pmax[r] = fmaxf(pmax[r], v);
      }
    }
#pragma unroll
    for (int r = 0; r < 4; ++r) {
#pragma unroll
      for (int msk = 1; msk <= 8; msk <<= 1)
        pmax[r] = fmaxf(pmax[r], __shfl_xor(pmax[r], msk));
    }
    float alpha[4], lsum[4];
#pragma unroll
    for (int r = 0; r < 4; ++r) {
      float mn = fmaxf(m_r[r], pmax[r]);
      alpha[r] = __expf(m_r[r] - mn);  // both -1e30 -> exp(0)=1, harmless (l=0)
      m_r[r] = mn;
      lsum[r] = 0.f;
    }
#pragma unroll
    for (int ct = 0; ct < 2; ++ct) {
#pragma unroll
      for (int r = 0; r < 4; ++r) {
        float v = sval[ct][r];
        float p = (v > -1e29f) ? __expf(v - m_r[r]) : 0.f;  // masked -> exactly 0
        lsum[r] += p;
        Pl[wid][(lg * 4 + r) * 40 + ct * 16 + lc] = f2bf(p);
      }
    }
#pragma unroll
    for (int r = 0; r < 4; ++r) {
#pragma unroll
      for (int msk = 1; msk <= 8; msk <<= 1) lsum[r] += __shfl_xor(lsum[r], msk);
      l_r[r] = l_r[r] * alpha[r] + lsum[r];
    }
#pragma unroll
    for (int dt = 0; dt < 16; ++dt) {
#pragma unroll
      for (int r = 0; r < 4; ++r) acc[dt][r] *= alpha[r];
    }
    asm volatile("s_waitcnt lgkmcnt(0)" ::: "memory");  // P writes visible in-wave
    const bf16x8 pa = *reinterpret_cast<const bf16x8*>(&Pl[wid][lc * 40 + lg * 8]);
    __builtin_amdgcn_s_setprio(1);
#pragma unroll
    for (int dt = 0; dt < 16; ++dt) {
      int d = dt * 16 + lc;
      const bf16x8 vf = *reinterpret_cast<const bf16x8*>(
          (const char*)Vl + (d * 64 + ((lg ^ ((d >> 1) & 3)) * 16)));
      acc[dt] = mfma16(pa, vf, acc[dt]);
    }
    __builtin_amdgcn_s_setprio(0);
    __syncthreads();
  }

  const int srow = q0 + wid * 16 + lg * 4;
#pragma unroll
  for (int dt = 0; dt < 16; ++dt) {
#pragma unroll
    for (int r = 0; r < 4; ++r) {
      float o = acc[dt][r] / l_r[r];
      O[(size_t)(b * S_ + srow + r) * (NH_ * HD_) + h * HD_ + dt * 16 + lc] =
          f2bf(o);
    }
  }
}

// ----------------------------------------------------------------- launch ----
extern "C" void kernel_launch(void* const* d_in, const int* in_sizes, int n_in,
                              void* d_out, int out_size, void* d_ws,
                              size_t ws_size, hipStream_t stream) {
  const float* hs = (const float*)d_in[0];
  const int* pos = (const int*)d_in[1];
  const float* Wq = (const float*)d_in[2];
  const float* bq = (const float*)d_in[3];
  const float* Wk = (const float*)d_in[4];
  const float* bk = (const float*)d_in[5];
  const float* Wv = (const float*)d_in[6];
  const float* bv = (const float*)d_in[7];
  const float* Wo = (const float*)d_in[8];
  float* out = (float*)d_out;

  char* ws = (char*)d_ws;
  const size_t MB = 1024 * 1024;
  unsigned short* hs_bf = (unsigned short*)(ws + 0);          // 32MB
  unsigned short* WqT   = (unsigned short*)(ws + 32 * MB);    // 8MB
  unsigned short* WkT   = (unsigned short*)(ws + 40 * MB);    // 4MB
  unsigned short* WvT   = (unsigned short*)(ws + 44 * MB);    // 4MB
  unsigned short* WoT   = (unsigned short*)(ws + 48 * MB);    // 8MB
  unsigned short* Qflat = (unsigned short*)(ws + 56 * MB);    // 32MB
  unsigned short* Kflat = (unsigned short*)(ws + 88 * MB);    // 16MB
  unsigned short* Vflat = (unsigned short*)(ws + 104 * MB);   // 16MB
  unsigned short* Qatt  = (unsigned short*)(ws + 120 * MB);   // 32MB
  unsigned short* Katt  = (unsigned short*)(ws + 152 * MB);   // 16MB
  unsigned short* VTt   = (unsigned short*)(ws + 168 * MB);   // 16MB
  unsigned short* attnb = (unsigned short*)(ws + 0);  // reuse hs_bf (dead)

  f32_to_bf16<<<2048, 256, 0, stream>>>(hs, hs_bf, (B_ * S_ * H_) / 4);
  transpose_w<<<dim3(H_ / 32, (NH_ * HD_) / 32), 256, 0, stream>>>(Wq, WqT, H_, NH_ * HD_);
  transpose_w<<<dim3(H_ / 32, (NKV_ * HD_) / 32), 256, 0, stream>>>(Wk, WkT, H_, NKV_ * HD_);
  transpose_w<<<dim3(H_ / 32, (NKV_ * HD_) / 32), 256, 0, stream>>>(Wv, WvT, H_, NKV_ * HD_);
  transpose_w<<<dim3((NH_ * HD_) / 32, H_ / 32), 256, 0, stream>>>(Wo, WoT, NH_ * HD_, H_);

  gemm_kernel<0><<<1024, 256, 0, stream>>>(hs_bf, WqT, bq, Qflat, 8192, 2048, 2048);
  gemm_kernel<0><<<512, 256, 0, stream>>>(hs_bf, WkT, bk, Kflat, 8192, 1024, 2048);
  gemm_kernel<0><<<512, 256, 0, stream>>>(hs_bf, WvT, bv, Vflat, 8192, 1024, 2048);

  rope_kernel<<<(B_ * S_ * 128) / 256, 256, 0, stream>>>(Qflat, pos, Qatt, NH_);
  rope_kernel<<<(B_ * S_ * 128) / 256, 256, 0, stream>>>(Kflat, pos, Katt, NKV_);
  transpose_v<<<dim3(S_ / 32, HD_ / 32, B_ * NKV_), 256, 0, stream>>>(Vflat, VTt);

  attn_kernel<<<dim3(32, 8, 4), 256, 0, stream>>>(Qatt, Katt, VTt, attnb);

  gemm_kernel<1><<<1024, 256, 0, stream>>>(attnb, WoT, nullptr, out, 8192, 2048, 2048);
}

// Round 4
// 647.651 us; speedup vs baseline: 1.3236x; 1.3236x over previous
//
#include <hip/hip_runtime.h>

#define B_ 4
#define S_ 2048
#define H_ 2048
#define NH_ 8
#define NKV_ 4
#define HD_ 256
#define WINDOW_ 1024
#define SCALE_ 0.0625f

typedef __bf16 bf16x8 __attribute__((ext_vector_type(8)));
typedef float f32x4 __attribute__((ext_vector_type(4)));

__device__ __forceinline__ unsigned short f2bf(float f) {
  union { float f; unsigned u; } v; v.f = f;
  unsigned r = v.u + 0x7fffu + ((v.u >> 16) & 1u);
  return (unsigned short)(r >> 16);
}
__device__ __forceinline__ float bf2f(unsigned short h) {
  union { unsigned u; float f; } v; v.u = ((unsigned)h) << 16;
  return v.f;
}

__device__ __forceinline__ f32x4 mfma16(bf16x8 a, bf16x8 b, f32x4 c) {
  return __builtin_amdgcn_mfma_f32_16x16x32_bf16(a, b, c, 0, 0, 0);
}

#define GLOAD16(gsrc, ldst)                                                     \
  __builtin_amdgcn_global_load_lds(                                             \
      (const __attribute__((address_space(1))) void*)(gsrc),                    \
      (__attribute__((address_space(3))) void*)(ldst), 16, 0, 0)

#define FENCE asm volatile("" ::: "memory")
#define BAR __builtin_amdgcn_s_barrier()
#define WAIT_LGKM0 asm volatile("s_waitcnt lgkmcnt(0)" ::: "memory")

// ---------------------------------------------------------------- convert ----
__global__ void f32_to_bf16(const float* __restrict__ in,
                            unsigned short* __restrict__ out, int n4) {
  int idx = blockIdx.x * blockDim.x + threadIdx.x;
  int stride = gridDim.x * blockDim.x;
  for (; idx < n4; idx += stride) {
    float4 v = reinterpret_cast<const float4*>(in)[idx];
    ushort4 o;
    o.x = f2bf(v.x); o.y = f2bf(v.y); o.z = f2bf(v.z); o.w = f2bf(v.w);
    reinterpret_cast<ushort4*>(out)[idx] = o;
  }
}

// in[R][C] fp32  ->  out[C][R] bf16
__global__ void transpose_w(const float* __restrict__ in,
                            unsigned short* __restrict__ out, int R, int C) {
  __shared__ unsigned short t[32][33];
  int r0 = blockIdx.x * 32, c0 = blockIdx.y * 32;
  int tx = threadIdx.x & 31, ty = threadIdx.x >> 5;  // ty 0..7
#pragma unroll
  for (int i = 0; i < 4; ++i)
    t[ty * 4 + i][tx] = f2bf(in[(size_t)(r0 + ty * 4 + i) * C + c0 + tx]);
  __syncthreads();
#pragma unroll
  for (int i = 0; i < 4; ++i)
    out[(size_t)(c0 + ty * 4 + i) * R + r0 + tx] = t[tx][ty * 4 + i];
}

// ----------------------------------------------------- 256^2 8-phase GEMM ----
// C[8192][2048] = A[8192][2048] * Bt[2048][2048]^T + bias
// 8 waves (2Mx4N), BK=64, dbuf 128KB dynamic LDS, counted vmcnt(6),
// st-swizzle (chunk ^= row&7) on stage-source + ds_read, T5 setprio.
// Stage ring: q0: A1(t+1) | q1: A0(t+2) | q2: B0(t+2) | q3: B1(t+2).
// vmcnt(6) at q3(t) leaves exactly {A0,B0,B1}(t+2) in flight => tile t+1
// fully resident before iteration t+1 reads it.

#define SA(buf, kt, ha)                                                        \
  { _Pragma("unroll") for (int ii = 0; ii < 2; ++ii) {                         \
      int row_ = ii * 128 + (ha) * 64 + (tid >> 3);                            \
      GLOAD16(gA + (((size_t)(m0 + row_)) << 11) + ((kt) << 6) +               \
                  ((((tid & 7) ^ ((tid >> 3) & 7))) << 3),                     \
              lds + (buf) * 65536 + ((ii * 128 + (ha) * 64 + wid * 8) << 7)); } }

#define SB(buf, kt, hb)                                                        \
  { _Pragma("unroll") for (int ii = 0; ii < 2; ++ii) {                         \
      int row_ = ii * 128 + (hb) * 64 + (tid >> 3);                            \
      GLOAD16(gB + (((size_t)(n0 + row_)) << 11) + ((kt) << 6) +               \
                  ((((tid & 7) ^ ((tid >> 3) & 7))) << 3),                     \
              lds + (buf) * 65536 + 32768 +                                    \
                  ((ii * 128 + (hb) * 64 + wid * 8) << 7)); } }

#define RDA(buf, qa)                                                           \
  { _Pragma("unroll") for (int m = 0; m < 4; ++m)                              \
      _Pragma("unroll") for (int ks = 0; ks < 2; ++ks)                         \
        afr[m][ks] = *reinterpret_cast<const bf16x8*>(                         \
            lds + (buf) * 65536 +                                              \
            ((wm * 128 + (qa) * 64 + m * 16 + lc) << 7) +                      \
            ((((ks * 4 + lg) ^ (lc & 7))) << 4)); }

#define RDB(buf, qb, dst)                                                      \
  { _Pragma("unroll") for (int n = 0; n < 2; ++n)                              \
      _Pragma("unroll") for (int ks = 0; ks < 2; ++ks)                         \
        dst[n][ks] = *reinterpret_cast<const bf16x8*>(                         \
            lds + (buf) * 65536 + 32768 +                                      \
            ((wn * 64 + (qb) * 32 + n * 16 + lc) << 7) +                       \
            ((((ks * 4 + lg) ^ (lc & 7))) << 4)); }

#define MM(qa, qb, bsrc)                                                       \
  { __builtin_amdgcn_s_setprio(1);                                             \
    _Pragma("unroll") for (int m = 0; m < 4; ++m)                              \
      _Pragma("unroll") for (int n = 0; n < 2; ++n)                            \
        _Pragma("unroll") for (int ks = 0; ks < 2; ++ks)                       \
          acc[qa][qb][m][n] =                                                  \
              mfma16(afr[m][ks], bsrc[n][ks], acc[qa][qb][m][n]);              \
    __builtin_amdgcn_s_setprio(0); }

template <int OUT_F32>
__global__ __launch_bounds__(512, 2) void gemm256(
    const unsigned short* __restrict__ gA, const unsigned short* __restrict__ gB,
    const float* __restrict__ bias, void* __restrict__ Cout) {
  extern __shared__ __align__(16) char lds[];
  const int tid = threadIdx.x, lane = tid & 63, wid = tid >> 6;
  const int lc = lane & 15, lg = lane >> 4;
  const int wm = wid >> 2, wn = wid & 3;  // 2M x 4N waves
  // XCD-aware 2D chunking: XCD c gets an 8mt x 4nt block of tiles.
  const int c = blockIdx.x & 7, bi = blockIdx.x >> 3;
  const int mt = ((c & 3) << 3) + (bi & 7);
  const int nt = ((c >> 2) << 2) + (bi >> 3);
  const int m0 = mt * 256, n0 = nt * 256;

  f32x4 acc[2][2][4][2];
#pragma unroll
  for (int qa = 0; qa < 2; ++qa)
#pragma unroll
    for (int qb = 0; qb < 2; ++qb)
#pragma unroll
      for (int m = 0; m < 4; ++m)
#pragma unroll
        for (int n = 0; n < 2; ++n) acc[qa][qb][m][n] = f32x4{0.f, 0.f, 0.f, 0.f};

  // Prologue: tile0 fully + A0,B0,B1 of tile1 (A1(1) comes from loop q0 @ t=0).
  SA(0, 0, 0); SB(0, 0, 0); SB(0, 0, 1); SA(0, 0, 1);
  SA(1, 1, 0); SB(1, 1, 0); SB(1, 1, 1);
  asm volatile("s_waitcnt vmcnt(6)" ::: "memory");
  FENCE; BAR;

  bf16x8 afr[4][2], b0r[2][2], b1r[2][2];
  for (int t = 0; t < 32; ++t) {
    const int b = t & 1;
    const int t1 = (t + 1) & 31, t2 = (t + 2) & 31;
    const int bn = (t + 1) & 1;
    // ---- q0: read A0+B0, stage A1(t+1), MFMA A0xB0
    RDA(b, 0); RDB(b, 0, b0r);
    SA(bn, t1, 1);
    FENCE; BAR;
    MM(0, 0, b0r);
    WAIT_LGKM0; FENCE; BAR;
    // ---- q1: read B1, stage A0(t+2), MFMA A0xB1
    RDB(b, 1, b1r);
    SA(b, t2, 0);
    FENCE; BAR;
    MM(0, 1, b1r);
    WAIT_LGKM0; FENCE; BAR;
    // ---- q2: read A1, stage B0(t+2), MFMA A1xB0
    RDA(b, 1);
    SB(b, t2, 0);
    FENCE; BAR;
    MM(1, 0, b0r);
    WAIT_LGKM0; FENCE; BAR;
    // ---- q3: stage B1(t+2), MFMA A1xB1, counted vmcnt
    SB(b, t2, 1);
    FENCE; BAR;
    MM(1, 1, b1r);
    asm volatile("s_waitcnt vmcnt(6)" ::: "memory");
    FENCE; BAR;
  }
  asm volatile("s_waitcnt vmcnt(0)" ::: "memory");

  // Epilogue: verified C/D layout (row = lg*4+r, col = lc within 16x16 tile)
#pragma unroll
  for (int qa = 0; qa < 2; ++qa)
#pragma unroll
    for (int qb = 0; qb < 2; ++qb)
#pragma unroll
      for (int m = 0; m < 4; ++m)
#pragma unroll
        for (int n = 0; n < 2; ++n) {
          const int gcol = n0 + wn * 64 + qb * 32 + n * 16 + lc;
          const float bv = bias ? bias[gcol] : 0.f;
          const int grow = m0 + wm * 128 + qa * 64 + m * 16 + lg * 4;
#pragma unroll
          for (int r = 0; r < 4; ++r) {
            float v = acc[qa][qb][m][n][r] + bv;
            if (OUT_F32)
              reinterpret_cast<float*>(Cout)[(size_t)(grow + r) * 2048 + gcol] = v;
            else
              reinterpret_cast<unsigned short*>(Cout)[(size_t)(grow + r) * 2048 + gcol] = f2bf(v);
          }
        }
}

// ------------------------------------------------------------------- RoPE ----
// in [B*S][2048] bf16 (heads at cols hh*256) -> out [B][nh][S][HD] bf16.
// One thread per (bs, d-pair); trig computed ONCE, reused across heads.
__global__ void rope_kernel(const unsigned short* __restrict__ in,
                            const int* __restrict__ pos,
                            unsigned short* __restrict__ out, int nh) {
  int idx = blockIdx.x * 256 + threadIdx.x;  // B*S*128 threads
  int d = idx & 127;
  int bs = idx >> 7;
  int b = bs >> 11, s = bs & 2047;
  float p = (float)pos[bs];
  float inv = __expf(-(float)d * (9.210340371976184f / 128.f));
  float fr = p * inv;
  float cs, sn;
  sincosf(fr, &sn, &cs);
  const unsigned short* ib = in + (size_t)bs * 2048 + d;
  unsigned short* ob = out + ((size_t)b * nh * S_ + s) * HD_ + d;
  for (int hh = 0; hh < nh; ++hh) {
    float x1 = bf2f(ib[hh * HD_]);
    float x2 = bf2f(ib[hh * HD_ + 128]);
    ob[(size_t)hh * S_ * HD_] = f2bf(x1 * cs - x2 * sn);
    ob[(size_t)hh * S_ * HD_ + 128] = f2bf(x2 * cs + x1 * sn);
  }
}

// V from merged KV buffer: in [B*S][2048] (V at cols 1024+hh*256) ->
// out [B][NKV][HD][S] bf16
__global__ void transpose_v(const unsigned short* __restrict__ in,
                            unsigned short* __restrict__ out) {
  __shared__ unsigned short t[32][33];
  int s0 = blockIdx.x * 32, d0 = blockIdx.y * 32;
  int bh = blockIdx.z;
  int b = bh >> 2, hh = bh & 3;
  int tx = threadIdx.x & 31, ty = threadIdx.x >> 5;
#pragma unroll
  for (int i = 0; i < 4; ++i)
    t[ty * 4 + i][tx] =
        in[(size_t)(b * S_ + s0 + ty * 4 + i) * 2048 + 1024 + hh * 256 + d0 + tx];
  __syncthreads();
#pragma unroll
  for (int i = 0; i < 4; ++i)
    out[((size_t)(b * NKV_ + hh) * HD_ + d0 + ty * 4 + i) * S_ + s0 + tx] =
        t[tx][ty * 4 + i];
}

// -------------------------------------------------------------- attention ----
// Q [B][NH][S][HD], K [B][NKV][S][HD], VT [B][NKV][HD][S] -> O [B*S][NH*HD]
// 512 threads = 8 waves: waves 0-3 handle head 2*kvh, waves 4-7 head 2*kvh+1,
// SHARING one staged K/V tile (halves staging traffic vs per-head blocks).
// Double-buffered staging with counted vmcnt(4) (T3 minimum 2-phase);
// defer-max rescale skip (T13, THR=8); descending-qt dispatch order.

#define STAGE_KV(bf, kv0)                                                      \
  { _Pragma("unroll") for (int i = 0; i < 2; ++i) {                            \
      int chunk = i * 512 + tid; int row = chunk >> 5, o = chunk & 31;         \
      GLOAD16(Kg0 + (size_t)((kv0) + row) * HD_ + (o ^ (row & 7)) * 8,         \
              (char*)&Kl[bf][0] + (i * 512 + wid * 64) * 16); }                \
    _Pragma("unroll") for (int i = 0; i < 2; ++i) {                            \
      int chunk = i * 512 + tid; int row = chunk >> 2, o = chunk & 3;          \
      GLOAD16(Vg0 + (size_t)row * S_ + (kv0) + (o ^ ((row >> 1) & 3)) * 8,     \
              (char*)&Vl[bf][0] + (i * 512 + wid * 64) * 16); } }

__global__ __launch_bounds__(512, 4) void attn_kernel(
    const unsigned short* __restrict__ Q, const unsigned short* __restrict__ K,
    const unsigned short* __restrict__ VT, unsigned short* __restrict__ O) {
  __shared__ __align__(16) unsigned short Kl[2][32 * 256];  // 2x16KB, swizzled
  __shared__ __align__(16) unsigned short Vl[2][256 * 32];  // 2x16KB, swizzled
  __shared__ __align__(16) unsigned short Pl[8][16 * 40];   // per-wave, +8 pad

  const int tid = threadIdx.x;
  const int lane = tid & 63, wid = tid >> 6;
  const int wq = wid & 3;   // q-row block within head
  const int ho = wid >> 2;  // which of the 2 q-heads sharing this kv head
  const int lc = lane & 15, lg = lane >> 4;
  const int qt = 31 - blockIdx.x;  // longest blocks dispatch first
  const int kvh = blockIdx.y, b = blockIdx.z;
  const int h = kvh * 2 + ho;
  const int q0 = qt * 64;

  // Q fragments: A[row=lc][k = ds*32 + lg*8 + j]
  bf16x8 qf[8];
  const unsigned short* Qbase =
      Q + (((size_t)(b * NH_ + h)) * S_ + (q0 + wq * 16 + lc)) * HD_;
#pragma unroll
  for (int ds = 0; ds < 8; ++ds)
    qf[ds] = *reinterpret_cast<const bf16x8*>(Qbase + ds * 32 + lg * 8);

  f32x4 acc[16];
#pragma unroll
  for (int i = 0; i < 16; ++i) acc[i] = f32x4{0.f, 0.f, 0.f, 0.f};
  float m_r[4], l_r[4];
#pragma unroll
  for (int r = 0; r < 4; ++r) { m_r[r] = -1e30f; l_r[r] = 0.f; }

  const unsigned short* Kg0 = K + ((size_t)(b * NKV_ + kvh)) * S_ * HD_;
  const unsigned short* Vg0 = VT + ((size_t)(b * NKV_ + kvh)) * HD_ * S_;

  int jlo = q0 - (WINDOW_ - 1);
  if (jlo < 0) jlo = 0;
  const int jt_lo = jlo >> 5;
  const int jt_hi = (q0 + 63) >> 5;
  const int ibase = q0 + wq * 16 + lg * 4;

  STAGE_KV(0, jt_lo * 32);
  int bf = 0;
  for (int jt = jt_lo; jt <= jt_hi; ++jt) {
    const int kv0 = jt * 32;
    if (jt < jt_hi) {
      STAGE_KV(bf ^ 1, (jt + 1) * 32);
      asm volatile("s_waitcnt vmcnt(4)" ::: "memory");  // tile jt resident
    } else {
      asm volatile("s_waitcnt vmcnt(0)" ::: "memory");
    }
    FENCE;
    __syncthreads();

    // S = Q K^T : B operand = K rows (swizzled read)
    f32x4 sf[2];
    __builtin_amdgcn_s_setprio(1);
#pragma unroll
    for (int ct = 0; ct < 2; ++ct) {
      f32x4 s{0.f, 0.f, 0.f, 0.f};
      int j = ct * 16 + lc;
#pragma unroll
      for (int ds = 0; ds < 8; ++ds) {
        int g = ds * 4 + lg;
        const bf16x8 kf = *reinterpret_cast<const bf16x8*>(
            (const char*)&Kl[bf][0] + (j * 512 + ((g ^ (j & 7)) * 16)));
        s = mfma16(qf[ds], kf, s);
      }
      sf[ct] = s;
    }
    __builtin_amdgcn_s_setprio(0);

    // row-max of masked, scaled scores
    float pmax[4];
#pragma unroll
    for (int r = 0; r < 4; ++r) pmax[r] = -1e30f;
#pragma unroll
    for (int ct = 0; ct < 2; ++ct) {
      int j = kv0 + ct * 16 + lc;
#pragma unroll
      for (int r = 0; r < 4; ++r) {
        int irow = ibase + r;
        bool ok = (j <= irow) && (j > irow - WINDOW_);
        pmax[r] = fmaxf(pmax[r], ok ? sf[ct][r] * SCALE_ : -1e30f);
      }
    }
#pragma unroll
    for (int r = 0; r < 4; ++r) {
#pragma unroll
      for (int msk = 1; msk <= 8; msk <<= 1)
        pmax[r] = fmaxf(pmax[r], __shfl_xor(pmax[r], msk));
    }
    // T13 defer-max: only rescale when the running max grew by > 8.
    float dmax = 0.f;
#pragma unroll
    for (int r = 0; r < 4; ++r) dmax = fmaxf(dmax, pmax[r] - m_r[r]);
    if (__any(dmax > 8.0f)) {
#pragma unroll
      for (int r = 0; r < 4; ++r) {
        float mn = fmaxf(m_r[r], pmax[r]);
        float a = __expf(m_r[r] - mn);  // -1e30 - -1e30 -> exp(0)=1, harmless
        m_r[r] = mn;
        l_r[r] *= a;
#pragma unroll
        for (int dt = 0; dt < 16; ++dt) acc[dt][r] *= a;
      }
    }
    // P = exp(S - m); masked -> exactly 0. Values bounded by e^8 (bf16-safe).
    float lsum[4];
#pragma unroll
    for (int r = 0; r < 4; ++r) lsum[r] = 0.f;
#pragma unroll
    for (int ct = 0; ct < 2; ++ct) {
      int j = kv0 + ct * 16 + lc;
#pragma unroll
      for (int r = 0; r < 4; ++r) {
        int irow = ibase + r;
        bool ok = (j <= irow) && (j > irow - WINDOW_);
        float p = ok ? __expf(sf[ct][r] * SCALE_ - m_r[r]) : 0.f;
        lsum[r] += p;
        Pl[wid][(lg * 4 + r) * 40 + ct * 16 + lc] = f2bf(p);
      }
    }
#pragma unroll
    for (int r = 0; r < 4; ++r) {
#pragma unroll
      for (int msk = 1; msk <= 8; msk <<= 1) lsum[r] += __shfl_xor(lsum[r], msk);
      l_r[r] += lsum[r];
    }
    WAIT_LGKM0;  // P writes visible (same-wave read)
    const bf16x8 pa = *reinterpret_cast<const bf16x8*>(&Pl[wid][lc * 40 + lg * 8]);
    __builtin_amdgcn_s_setprio(1);
#pragma unroll
    for (int dt = 0; dt < 16; ++dt) {
      int d = dt * 16 + lc;
      const bf16x8 vf = *reinterpret_cast<const bf16x8*>(
          (const char*)&Vl[bf][0] + (d * 64 + ((lg ^ ((d >> 1) & 3)) * 16)));
      acc[dt] = mfma16(pa, vf, acc[dt]);
    }
    __builtin_amdgcn_s_setprio(0);
    WAIT_LGKM0; FENCE;
    __syncthreads();  // all waves' LDS reads done before next overwrite
    bf ^= 1;
  }

  const int srow = q0 + wq * 16 + lg * 4;
#pragma unroll
  for (int dt = 0; dt < 16; ++dt) {
#pragma unroll
    for (int r = 0; r < 4; ++r) {
      float o = acc[dt][r] / l_r[r];
      O[(size_t)(b * S_ + srow + r) * (NH_ * HD_) + h * HD_ + dt * 16 + lc] =
          f2bf(o);
    }
  }
}

// ----------------------------------------------------------------- launch ----
extern "C" void kernel_launch(void* const* d_in, const int* in_sizes, int n_in,
                              void* d_out, int out_size, void* d_ws,
                              size_t ws_size, hipStream_t stream) {
  (void)in_sizes; (void)n_in; (void)out_size; (void)ws_size;
  const float* hs = (const float*)d_in[0];
  const int* pos = (const int*)d_in[1];
  const float* Wq = (const float*)d_in[2];
  const float* bq = (const float*)d_in[3];
  const float* Wk = (const float*)d_in[4];
  const float* bk = (const float*)d_in[5];
  const float* Wv = (const float*)d_in[6];
  const float* bv = (const float*)d_in[7];
  const float* Wo = (const float*)d_in[8];
  float* out = (float*)d_out;

  char* ws = (char*)d_ws;
  const size_t MB = 1024 * 1024;
  unsigned short* hs_bf = (unsigned short*)(ws + 0);          // 32MB
  unsigned short* WqT   = (unsigned short*)(ws + 32 * MB);    // 8MB
  unsigned short* WkvT  = (unsigned short*)(ws + 40 * MB);    // 8MB (Wk^T||Wv^T)
  unsigned short* WoT   = (unsigned short*)(ws + 48 * MB);    // 8MB
  unsigned short* Qflat = (unsigned short*)(ws + 56 * MB);    // 32MB
  unsigned short* KVflat= (unsigned short*)(ws + 88 * MB);    // 32MB
  unsigned short* Qatt  = (unsigned short*)(ws + 120 * MB);   // 32MB
  unsigned short* Katt  = (unsigned short*)(ws + 152 * MB);   // 16MB
  unsigned short* VTt   = (unsigned short*)(ws + 168 * MB);   // 16MB
  float* bias_kv = (float*)(ws + 120 * MB);  // transient: dead before Qatt written
  unsigned short* attnb = (unsigned short*)(ws + 0);  // reuse hs_bf (dead)

  // Opt into 128KB dynamic LDS for the 8-phase GEMM (idempotent).
  hipFuncSetAttribute(reinterpret_cast<const void*>(gemm256<0>),
                      hipFuncAttributeMaxDynamicSharedMemorySize, 131072);
  hipFuncSetAttribute(reinterpret_cast<const void*>(gemm256<1>),
                      hipFuncAttributeMaxDynamicSharedMemorySize, 131072);

  f32_to_bf16<<<2048, 256, 0, stream>>>(hs, hs_bf, (B_ * S_ * H_) / 4);
  transpose_w<<<dim3(H_ / 32, (NH_ * HD_) / 32), 256, 0, stream>>>(Wq, WqT, H_, NH_ * HD_);
  transpose_w<<<dim3(H_ / 32, (NKV_ * HD_) / 32), 256, 0, stream>>>(Wk, WkvT, H_, NKV_ * HD_);
  transpose_w<<<dim3(H_ / 32, (NKV_ * HD_) / 32), 256, 0, stream>>>(Wv, WkvT + 1024 * 2048, H_, NKV_ * HD_);
  transpose_w<<<dim3((NH_ * HD_) / 32, H_ / 32), 256, 0, stream>>>(Wo, WoT, NH_ * HD_, H_);
  hipMemcpyAsync(bias_kv, bk, 1024 * sizeof(float), hipMemcpyDeviceToDevice, stream);
  hipMemcpyAsync(bias_kv + 1024, bv, 1024 * sizeof(float), hipMemcpyDeviceToDevice, stream);

  gemm256<0><<<256, 512, 131072, stream>>>(hs_bf, WqT, bq, Qflat);
  gemm256<0><<<256, 512, 131072, stream>>>(hs_bf, WkvT, bias_kv, KVflat);

  rope_kernel<<<(B_ * S_ * 128) / 256, 256, 0, stream>>>(Qflat, pos, Qatt, NH_);
  rope_kernel<<<(B_ * S_ * 128) / 256, 256, 0, stream>>>(KVflat, pos, Katt, NKV_);
  transpose_v<<<dim3(S_ / 32, HD_ / 32, B_ * NKV_), 256, 0, stream>>>(KVflat, VTt);

  attn_kernel<<<dim3(32, 4, 4), 512, 0, stream>>>(Qatt, Katt, VTt, attnb);

  gemm256<1><<<256, 512, 131072, stream>>>(attnb, WoT, nullptr, out);
}

// Round 5
// 539.387 us; speedup vs baseline: 1.5892x; 1.2007x over previous
//
#include <hip/hip_runtime.h>

#define B_ 4
#define S_ 2048
#define H_ 2048
#define NH_ 8
#define NKV_ 4
#define HD_ 256
#define WINDOW_ 1024
#define SCALE_ 0.0625f

typedef __bf16 bf16x8 __attribute__((ext_vector_type(8)));
typedef float f32x4 __attribute__((ext_vector_type(4)));

__device__ __forceinline__ unsigned short f2bf(float f) {
  union { float f; unsigned u; } v; v.f = f;
  unsigned r = v.u + 0x7fffu + ((v.u >> 16) & 1u);
  return (unsigned short)(r >> 16);
}
__device__ __forceinline__ float bf2f(unsigned short h) {
  union { unsigned u; float f; } v; v.u = ((unsigned)h) << 16;
  return v.f;
}

__device__ __forceinline__ f32x4 mfma16(bf16x8 a, bf16x8 b, f32x4 c) {
  return __builtin_amdgcn_mfma_f32_16x16x32_bf16(a, b, c, 0, 0, 0);
}

#define GLOAD16(gsrc, ldst)                                                     \
  __builtin_amdgcn_global_load_lds(                                             \
      (const __attribute__((address_space(1))) void*)(gsrc),                    \
      (__attribute__((address_space(3))) void*)(ldst), 16, 0, 0)

#define FENCE asm volatile("" ::: "memory")
#define BAR __builtin_amdgcn_s_barrier()
#define WAIT_LGKM0 asm volatile("s_waitcnt lgkmcnt(0)" ::: "memory")

// ---------------------------------------------------------------- convert ----
__global__ void f32_to_bf16(const float* __restrict__ in,
                            unsigned short* __restrict__ out, int n4) {
  int idx = blockIdx.x * blockDim.x + threadIdx.x;
  int stride = gridDim.x * blockDim.x;
  for (; idx < n4; idx += stride) {
    float4 v = reinterpret_cast<const float4*>(in)[idx];
    ushort4 o;
    o.x = f2bf(v.x); o.y = f2bf(v.y); o.z = f2bf(v.z); o.w = f2bf(v.w);
    reinterpret_cast<ushort4*>(out)[idx] = o;
  }
}

// in[R][C] fp32  ->  out[C][R] bf16
__global__ void transpose_w(const float* __restrict__ in,
                            unsigned short* __restrict__ out, int R, int C) {
  __shared__ unsigned short t[32][33];
  int r0 = blockIdx.x * 32, c0 = blockIdx.y * 32;
  int tx = threadIdx.x & 31, ty = threadIdx.x >> 5;  // ty 0..7
#pragma unroll
  for (int i = 0; i < 4; ++i)
    t[ty * 4 + i][tx] = f2bf(in[(size_t)(r0 + ty * 4 + i) * C + c0 + tx]);
  __syncthreads();
#pragma unroll
  for (int i = 0; i < 4; ++i)
    out[(size_t)(c0 + ty * 4 + i) * R + r0 + tx] = t[tx][ty * 4 + i];
}

// ----------------------------------------------------- 256^2 8-phase GEMM ----
// C[8192][NTILES*256] = A[8192][2048] * Bt[NTILES*256][2048]^T + bias
// 8 waves (2Mx4N), BK=64, dbuf 128KB dynamic LDS, counted vmcnt(6),
// st-swizzle (chunk ^= row&7) on stage-source + ds_read, T5 setprio.
// Stage ring: q0: A1(t+1) | q1: A0(t+2) | q2: B0(t+2) | q3: B1(t+2).
// vmcnt(6) at q3(t) leaves exactly {A0,B0,B1}(t+2) in flight => tile t+1
// fully resident before iteration t+1 reads it.

#define SA(buf, kt, ha)                                                        \
  { _Pragma("unroll") for (int ii = 0; ii < 2; ++ii) {                         \
      int row_ = ii * 128 + (ha) * 64 + (tid >> 3);                            \
      GLOAD16(gA + (((size_t)(m0 + row_)) << 11) + ((kt) << 6) +               \
                  ((((tid & 7) ^ ((tid >> 3) & 7))) << 3),                     \
              lds + (buf) * 65536 + ((ii * 128 + (ha) * 64 + wid * 8) << 7)); } }

#define SB(buf, kt, hb)                                                        \
  { _Pragma("unroll") for (int ii = 0; ii < 2; ++ii) {                         \
      int row_ = ii * 128 + (hb) * 64 + (tid >> 3);                            \
      GLOAD16(gB + (((size_t)(n0 + row_)) << 11) + ((kt) << 6) +               \
                  ((((tid & 7) ^ ((tid >> 3) & 7))) << 3),                     \
              lds + (buf) * 65536 + 32768 +                                    \
                  ((ii * 128 + (hb) * 64 + wid * 8) << 7)); } }

#define RDA(buf, qa)                                                           \
  { _Pragma("unroll") for (int m = 0; m < 4; ++m)                              \
      _Pragma("unroll") for (int ks = 0; ks < 2; ++ks)                         \
        afr[m][ks] = *reinterpret_cast<const bf16x8*>(                         \
            lds + (buf) * 65536 +                                              \
            ((wm * 128 + (qa) * 64 + m * 16 + lc) << 7) +                      \
            ((((ks * 4 + lg) ^ (lc & 7))) << 4)); }

#define RDB(buf, qb, dst)                                                      \
  { _Pragma("unroll") for (int n = 0; n < 2; ++n)                              \
      _Pragma("unroll") for (int ks = 0; ks < 2; ++ks)                         \
        dst[n][ks] = *reinterpret_cast<const bf16x8*>(                         \
            lds + (buf) * 65536 + 32768 +                                      \
            ((wn * 64 + (qb) * 32 + n * 16 + lc) << 7) +                       \
            ((((ks * 4 + lg) ^ (lc & 7))) << 4)); }

#define MM(qa, qb, bsrc)                                                       \
  { __builtin_amdgcn_s_setprio(1);                                             \
    _Pragma("unroll") for (int m = 0; m < 4; ++m)                              \
      _Pragma("unroll") for (int n = 0; n < 2; ++n)                            \
        _Pragma("unroll") for (int ks = 0; ks < 2; ++ks)                       \
          acc[qa][qb][m][n] =                                                  \
              mfma16(afr[m][ks], bsrc[n][ks], acc[qa][qb][m][n]);              \
    __builtin_amdgcn_s_setprio(0); }

template <int OUT_F32, int NTILES>
__global__ __launch_bounds__(512, 2) void gemm256(
    const unsigned short* __restrict__ gA, const unsigned short* __restrict__ gB,
    const float* __restrict__ bias, void* __restrict__ Cout) {
  extern __shared__ __align__(16) char lds[];
  const int tid = threadIdx.x, lane = tid & 63, wid = tid >> 6;
  const int lc = lane & 15, lg = lane >> 4;
  const int wm = wid >> 2, wn = wid & 3;  // 2M x 4N waves
  const int N_ = NTILES * 256;
  // XCD-aware 2D chunking: XCD c gets a 8mt x (NTILES/2)nt block of tiles.
  const int c = blockIdx.x & 7, bi = blockIdx.x >> 3;
  const int mt = ((c & 3) << 3) + (bi & 7);
  const int nt = ((c >> 2) * (NTILES / 2)) + (bi >> 3);
  const int m0 = mt * 256, n0 = nt * 256;

  f32x4 acc[2][2][4][2];
#pragma unroll
  for (int qa = 0; qa < 2; ++qa)
#pragma unroll
    for (int qb = 0; qb < 2; ++qb)
#pragma unroll
      for (int m = 0; m < 4; ++m)
#pragma unroll
        for (int n = 0; n < 2; ++n) acc[qa][qb][m][n] = f32x4{0.f, 0.f, 0.f, 0.f};

  // Prologue: tile0 fully + A0,B0,B1 of tile1 (A1(1) comes from loop q0 @ t=0).
  SA(0, 0, 0); SB(0, 0, 0); SB(0, 0, 1); SA(0, 0, 1);
  SA(1, 1, 0); SB(1, 1, 0); SB(1, 1, 1);
  asm volatile("s_waitcnt vmcnt(6)" ::: "memory");
  FENCE; BAR;

  bf16x8 afr[4][2], b0r[2][2], b1r[2][2];
  for (int t = 0; t < 32; ++t) {
    const int b = t & 1;
    const int t1 = (t + 1) & 31, t2 = (t + 2) & 31;
    const int bn = (t + 1) & 1;
    // ---- q0: read A0+B0, stage A1(t+1), MFMA A0xB0
    RDA(b, 0); RDB(b, 0, b0r);
    SA(bn, t1, 1);
    FENCE; BAR;
    MM(0, 0, b0r);
    WAIT_LGKM0; FENCE; BAR;
    // ---- q1: read B1, stage A0(t+2), MFMA A0xB1
    RDB(b, 1, b1r);
    SA(b, t2, 0);
    FENCE; BAR;
    MM(0, 1, b1r);
    WAIT_LGKM0; FENCE; BAR;
    // ---- q2: read A1, stage B0(t+2), MFMA A1xB0
    RDA(b, 1);
    SB(b, t2, 0);
    FENCE; BAR;
    MM(1, 0, b0r);
    WAIT_LGKM0; FENCE; BAR;
    // ---- q3: stage B1(t+2), MFMA A1xB1, counted vmcnt
    SB(b, t2, 1);
    FENCE; BAR;
    MM(1, 1, b1r);
    asm volatile("s_waitcnt vmcnt(6)" ::: "memory");
    FENCE; BAR;
  }
  asm volatile("s_waitcnt vmcnt(0)" ::: "memory");

  // Epilogue: verified C/D layout (row = lg*4+r, col = lc within 16x16 tile)
#pragma unroll
  for (int qa = 0; qa < 2; ++qa)
#pragma unroll
    for (int qb = 0; qb < 2; ++qb)
#pragma unroll
      for (int m = 0; m < 4; ++m)
#pragma unroll
        for (int n = 0; n < 2; ++n) {
          const int gcol = n0 + wn * 64 + qb * 32 + n * 16 + lc;
          const float bv = bias ? bias[gcol] : 0.f;
          const int grow = m0 + wm * 128 + qa * 64 + m * 16 + lg * 4;
#pragma unroll
          for (int r = 0; r < 4; ++r) {
            float v = acc[qa][qb][m][n][r] + bv;
            if (OUT_F32)
              reinterpret_cast<float*>(Cout)[(size_t)(grow + r) * N_ + gcol] = v;
            else
              reinterpret_cast<unsigned short*>(Cout)[(size_t)(grow + r) * N_ + gcol] = f2bf(v);
          }
        }
}

// ------------------------------------------------------------------- RoPE ----
// in [B*S][4096] bf16 (heads at cols colbase+hh*256) -> out [B][nh][S][HD].
// One thread per (bs, d-pair); trig computed ONCE, reused across heads.
__global__ void rope_kernel(const unsigned short* __restrict__ in,
                            const int* __restrict__ pos,
                            unsigned short* __restrict__ out, int nh,
                            int colbase) {
  int idx = blockIdx.x * 256 + threadIdx.x;  // B*S*128 threads
  int d = idx & 127;
  int bs = idx >> 7;
  int b = bs >> 11, s = bs & 2047;
  float p = (float)pos[bs];
  float inv = __expf(-(float)d * (9.210340371976184f / 128.f));
  float fr = p * inv;
  float cs, sn;
  sincosf(fr, &sn, &cs);
  const unsigned short* ib = in + (size_t)bs * 4096 + colbase + d;
  unsigned short* ob = out + ((size_t)b * nh * S_ + s) * HD_ + d;
  for (int hh = 0; hh < nh; ++hh) {
    float x1 = bf2f(ib[hh * HD_]);
    float x2 = bf2f(ib[hh * HD_ + 128]);
    ob[(size_t)hh * S_ * HD_] = f2bf(x1 * cs - x2 * sn);
    ob[(size_t)hh * S_ * HD_ + 128] = f2bf(x2 * cs + x1 * sn);
  }
}

// V from merged QKV buffer: in [B*S][4096] (V at cols 3072+hh*256) ->
// out [B][NKV][HD][S] bf16
__global__ void transpose_v(const unsigned short* __restrict__ in,
                            unsigned short* __restrict__ out) {
  __shared__ unsigned short t[32][33];
  int s0 = blockIdx.x * 32, d0 = blockIdx.y * 32;
  int bh = blockIdx.z;
  int b = bh >> 2, hh = bh & 3;
  int tx = threadIdx.x & 31, ty = threadIdx.x >> 5;
#pragma unroll
  for (int i = 0; i < 4; ++i)
    t[ty * 4 + i][tx] =
        in[(size_t)(b * S_ + s0 + ty * 4 + i) * 4096 + 3072 + hh * 256 + d0 + tx];
  __syncthreads();
#pragma unroll
  for (int i = 0; i < 4; ++i)
    out[((size_t)(b * NKV_ + hh) * HD_ + d0 + ty * 4 + i) * S_ + s0 + tx] =
        t[tx][ty * 4 + i];
}

// -------------------------------------------------------------- attention ----
// Q [B][NH][S][HD], K [B][NKV][S][HD], VT [B][NKV][HD][S] -> O [B*S][NH*HD]
// 512 threads = 8 waves: waves 0-3 head 2*kvh, waves 4-7 head 2*kvh+1, sharing
// one staged K/V tile. KVBLK=64, double-buffered, counted vmcnt(8).
// Dynamic LDS 146KB: K 2x32KB | V 2x32KB | P 8x4.5KB.
// XCD-phase swizzle: XCD x runs all 32 qt-blocks of pair x first (4MB = L2),
// then pair x+8; qt descending so longest blocks start first.

#define STAGE_KV(bfb, kv0)                                                     \
  { _Pragma("unroll") for (int i = 0; i < 4; ++i) {                            \
      int chunk = i * 512 + tid; int row = chunk >> 5, o = chunk & 31;         \
      GLOAD16(Kg0 + (size_t)((kv0) + row) * HD_ + (o ^ (row & 7)) * 8,         \
              lds + (bfb) * 32768 + chunk * 16); }                             \
    _Pragma("unroll") for (int i = 0; i < 4; ++i) {                            \
      int chunk = i * 512 + tid; int row = chunk >> 3, o = chunk & 7;          \
      GLOAD16(Vg0 + (size_t)row * S_ + (kv0) + (o ^ (row & 7)) * 8,            \
              lds + 65536 + (bfb) * 32768 + chunk * 16); } }

__global__ __launch_bounds__(512, 1) void attn_kernel(
    const unsigned short* __restrict__ Q, const unsigned short* __restrict__ K,
    const unsigned short* __restrict__ VT, unsigned short* __restrict__ O) {
  extern __shared__ __align__(16) char lds[];

  const int tid = threadIdx.x;
  const int lane = tid & 63, wid = tid >> 6;
  const int wq = wid & 3;   // q-row block within head
  const int ho = wid >> 2;  // which of the 2 q-heads sharing this kv head
  const int lc = lane & 15, lg = lane >> 4;
  // XCD-phase swizzle
  const int xcd = blockIdx.x & 7, g = blockIdx.x >> 3;
  const int pair = xcd + ((g >> 5) << 3);  // 0..15
  const int qt = 31 - (g & 31);
  const int kvh = pair & 3, b = pair >> 2;
  const int h = kvh * 2 + ho;
  const int q0 = qt * 64;
  unsigned short* Pl = (unsigned short*)(lds + 131072 + wid * 2304);

  // Q fragments: A[row=lc][k = ds*32 + lg*8 + j]
  bf16x8 qf[8];
  const unsigned short* Qbase =
      Q + (((size_t)(b * NH_ + h)) * S_ + (q0 + wq * 16 + lc)) * HD_;
#pragma unroll
  for (int ds = 0; ds < 8; ++ds)
    qf[ds] = *reinterpret_cast<const bf16x8*>(Qbase + ds * 32 + lg * 8);

  f32x4 acc[16];
#pragma unroll
  for (int i = 0; i < 16; ++i) acc[i] = f32x4{0.f, 0.f, 0.f, 0.f};
  float m_r[4], l_r[4];
#pragma unroll
  for (int r = 0; r < 4; ++r) { m_r[r] = -1e30f; l_r[r] = 0.f; }

  const unsigned short* Kg0 = K + ((size_t)(b * NKV_ + kvh)) * S_ * HD_;
  const unsigned short* Vg0 = VT + ((size_t)(b * NKV_ + kvh)) * HD_ * S_;

  int jlo = q0 - (WINDOW_ - 1);
  if (jlo < 0) jlo = 0;
  const int jt_lo = jlo >> 6;
  const int jt_hi = q0 >> 6;  // (q0+63)>>6 == qt
  const int ibase = q0 + wq * 16 + lg * 4;

  STAGE_KV(0, jt_lo * 64);
  int bf = 0;
  for (int jt = jt_lo; jt <= jt_hi; ++jt) {
    const int kv0 = jt * 64;
    if (jt < jt_hi) {
      STAGE_KV(bf ^ 1, (jt + 1) * 64);
      asm volatile("s_waitcnt vmcnt(8)" ::: "memory");  // tile jt resident
    } else {
      asm volatile("s_waitcnt vmcnt(0)" ::: "memory");
    }
    FENCE;
    __syncthreads();

    // S = Q K^T : B operand = K rows (swizzled read)
    f32x4 sf[4];
    __builtin_amdgcn_s_setprio(1);
#pragma unroll
    for (int ct = 0; ct < 4; ++ct) {
      f32x4 s{0.f, 0.f, 0.f, 0.f};
      int j = ct * 16 + lc;
#pragma unroll
      for (int ds = 0; ds < 8; ++ds) {
        int gg = ds * 4 + lg;
        const bf16x8 kf = *reinterpret_cast<const bf16x8*>(
            lds + bf * 32768 + j * 512 + ((gg ^ (j & 7)) * 16));
        s = mfma16(qf[ds], kf, s);
      }
      sf[ct] = s;
    }
    __builtin_amdgcn_s_setprio(0);

    // row-max of masked, scaled scores
    float pmax[4];
#pragma unroll
    for (int r = 0; r < 4; ++r) pmax[r] = -1e30f;
#pragma unroll
    for (int ct = 0; ct < 4; ++ct) {
      int j = kv0 + ct * 16 + lc;
#pragma unroll
      for (int r = 0; r < 4; ++r) {
        int irow = ibase + r;
        bool ok = (j <= irow) && (j > irow - WINDOW_);
        pmax[r] = fmaxf(pmax[r], ok ? sf[ct][r] * SCALE_ : -1e30f);
      }
    }
#pragma unroll
    for (int r = 0; r < 4; ++r) {
#pragma unroll
      for (int msk = 1; msk <= 8; msk <<= 1)
        pmax[r] = fmaxf(pmax[r], __shfl_xor(pmax[r], msk));
    }
    // T13 defer-max: only rescale when the running max grew by > 8.
    float dmax = 0.f;
#pragma unroll
    for (int r = 0; r < 4; ++r) dmax = fmaxf(dmax, pmax[r] - m_r[r]);
    if (__any(dmax > 8.0f)) {
#pragma unroll
      for (int r = 0; r < 4; ++r) {
        float mn = fmaxf(m_r[r], pmax[r]);
        float a = __expf(m_r[r] - mn);  // -1e30 - -1e30 -> exp(0)=1, harmless
        m_r[r] = mn;
        l_r[r] *= a;
#pragma unroll
        for (int dt = 0; dt < 16; ++dt) acc[dt][r] *= a;
      }
    }
    // P = exp(S - m); masked -> exactly 0. Values bounded by e^8 (bf16-safe).
    float lsum[4];
#pragma unroll
    for (int r = 0; r < 4; ++r) lsum[r] = 0.f;
#pragma unroll
    for (int ct = 0; ct < 4; ++ct) {
      int j = kv0 + ct * 16 + lc;
#pragma unroll
      for (int r = 0; r < 4; ++r) {
        int irow = ibase + r;
        bool ok = (j <= irow) && (j > irow - WINDOW_);
        float p = ok ? __expf(sf[ct][r] * SCALE_ - m_r[r]) : 0.f;
        lsum[r] += p;
        Pl[(lg * 4 + r) * 72 + ct * 16 + lc] = f2bf(p);
      }
    }
#pragma unroll
    for (int r = 0; r < 4; ++r) {
#pragma unroll
      for (int msk = 1; msk <= 8; msk <<= 1) lsum[r] += __shfl_xor(lsum[r], msk);
      l_r[r] += lsum[r];
    }
    WAIT_LGKM0;  // P writes visible (same-wave read)
    bf16x8 pa0 = *reinterpret_cast<const bf16x8*>(&Pl[lc * 72 + lg * 8]);
    bf16x8 pa1 = *reinterpret_cast<const bf16x8*>(&Pl[lc * 72 + 32 + lg * 8]);
    __builtin_amdgcn_s_setprio(1);
#pragma unroll
    for (int dt = 0; dt < 16; ++dt) {
      int d = dt * 16 + lc;
      const bf16x8 vf0 = *reinterpret_cast<const bf16x8*>(
          lds + 65536 + bf * 32768 + d * 128 + ((lg ^ (d & 7)) * 16));
      const bf16x8 vf1 = *reinterpret_cast<const bf16x8*>(
          lds + 65536 + bf * 32768 + d * 128 + (((4 + lg) ^ (d & 7)) * 16));
      acc[dt] = mfma16(pa0, vf0, acc[dt]);
      acc[dt] = mfma16(pa1, vf1, acc[dt]);
    }
    __builtin_amdgcn_s_setprio(0);
    WAIT_LGKM0; FENCE;
    __syncthreads();  // all waves' LDS reads done before next overwrite
    bf ^= 1;
  }

  const int srow = q0 + wq * 16 + lg * 4;
#pragma unroll
  for (int dt = 0; dt < 16; ++dt) {
#pragma unroll
    for (int r = 0; r < 4; ++r) {
      float o = acc[dt][r] / l_r[r];
      O[(size_t)(b * S_ + srow + r) * (NH_ * HD_) + h * HD_ + dt * 16 + lc] =
          f2bf(o);
    }
  }
}

// ----------------------------------------------------------------- launch ----
extern "C" void kernel_launch(void* const* d_in, const int* in_sizes, int n_in,
                              void* d_out, int out_size, void* d_ws,
                              size_t ws_size, hipStream_t stream) {
  (void)in_sizes; (void)n_in; (void)out_size; (void)ws_size;
  const float* hs = (const float*)d_in[0];
  const int* pos = (const int*)d_in[1];
  const float* Wq = (const float*)d_in[2];
  const float* bq = (const float*)d_in[3];
  const float* Wk = (const float*)d_in[4];
  const float* bk = (const float*)d_in[5];
  const float* Wv = (const float*)d_in[6];
  const float* bv = (const float*)d_in[7];
  const float* Wo = (const float*)d_in[8];
  float* out = (float*)d_out;

  char* ws = (char*)d_ws;
  const size_t MB = 1024 * 1024;
  unsigned short* hs_bf  = (unsigned short*)(ws + 0);          // 32MB
  unsigned short* WqkvT  = (unsigned short*)(ws + 32 * MB);    // 16MB (Wq||Wk||Wv)^T
  unsigned short* WoT    = (unsigned short*)(ws + 48 * MB);    // 8MB
  unsigned short* QKVflat= (unsigned short*)(ws + 56 * MB);    // 64MB [8192][4096]
  unsigned short* Qatt   = (unsigned short*)(ws + 120 * MB);   // 32MB
  unsigned short* Katt   = (unsigned short*)(ws + 152 * MB);   // 16MB
  unsigned short* VTt    = (unsigned short*)(ws + 168 * MB);   // 16MB
  float* bias_qkv = (float*)(ws + 120 * MB);  // transient: dead before Qatt
  unsigned short* attnb  = (unsigned short*)(ws + 0);  // reuse hs_bf (dead)

  hipFuncSetAttribute(reinterpret_cast<const void*>(gemm256<0, 16>),
                      hipFuncAttributeMaxDynamicSharedMemorySize, 131072);
  hipFuncSetAttribute(reinterpret_cast<const void*>(gemm256<1, 8>),
                      hipFuncAttributeMaxDynamicSharedMemorySize, 131072);
  hipFuncSetAttribute(reinterpret_cast<const void*>(attn_kernel),
                      hipFuncAttributeMaxDynamicSharedMemorySize, 149504);

  f32_to_bf16<<<2048, 256, 0, stream>>>(hs, hs_bf, (B_ * S_ * H_) / 4);
  transpose_w<<<dim3(H_ / 32, 2048 / 32), 256, 0, stream>>>(Wq, WqkvT, H_, 2048);
  transpose_w<<<dim3(H_ / 32, 1024 / 32), 256, 0, stream>>>(Wk, WqkvT + 2048 * 2048, H_, 1024);
  transpose_w<<<dim3(H_ / 32, 1024 / 32), 256, 0, stream>>>(Wv, WqkvT + 3072 * 2048, H_, 1024);
  transpose_w<<<dim3(2048 / 32, H_ / 32), 256, 0, stream>>>(Wo, WoT, 2048, H_);
  hipMemcpyAsync(bias_qkv, bq, 2048 * sizeof(float), hipMemcpyDeviceToDevice, stream);
  hipMemcpyAsync(bias_qkv + 2048, bk, 1024 * sizeof(float), hipMemcpyDeviceToDevice, stream);
  hipMemcpyAsync(bias_qkv + 3072, bv, 1024 * sizeof(float), hipMemcpyDeviceToDevice, stream);

  // Merged QKV projection: [8192][2048] x [4096][2048]^T -> [8192][4096]
  gemm256<0, 16><<<512, 512, 131072, stream>>>(hs_bf, WqkvT, bias_qkv, QKVflat);

  rope_kernel<<<(B_ * S_ * 128) / 256, 256, 0, stream>>>(QKVflat, pos, Qatt, NH_, 0);
  rope_kernel<<<(B_ * S_ * 128) / 256, 256, 0, stream>>>(QKVflat, pos, Katt, NKV_, 2048);
  transpose_v<<<dim3(S_ / 32, HD_ / 32, B_ * NKV_), 256, 0, stream>>>(QKVflat, VTt);

  attn_kernel<<<512, 512, 149504, stream>>>(Qatt, Katt, VTt, attnb);

  gemm256<1, 8><<<256, 512, 131072, stream>>>(attnb, WoT, nullptr, out);
}